// Round 13
// baseline (2317.649 us; speedup 1.0000x reference)
//
#include <hip/hip_runtime.h>
#include <hip/hip_bf16.h>
#include <math.h>

#define NB   8192
#define TSRC 48
#define TTGT 12
#define ROWS 32      // encoder rows/block
#define DR   16      // decoder rows/block

typedef float f32x4 __attribute__((ext_vector_type(4)));
typedef float f32x2 __attribute__((ext_vector_type(2)));
typedef short bf16x8 __attribute__((ext_vector_type(8)));
typedef short bf16x4 __attribute__((ext_vector_type(4)));
typedef unsigned u32x2 __attribute__((ext_vector_type(2)));

#define QSCALE 2.8853900817779268f   // 2*log2(e)

__device__ __forceinline__ float bf2f(unsigned short u){ return __uint_as_float(((unsigned)u)<<16); }
__device__ __forceinline__ unsigned short f2bf(float f){
  unsigned u = __float_as_uint(f);
  u += 0x7fffu + ((u>>16)&1u);
  return (unsigned short)(u>>16);
}
__device__ __forceinline__ float sigm(float x){ return 1.0f/(1.0f+__expf(-x)); }
__device__ __forceinline__ float tanhfast(float x){
  float a = fminf(fabsf(x), 15.0f);
  float e = __expf(2.0f*a);
  float r = 1.0f - 2.0f/(e+1.0f);
  return copysignf(r, x);
}
__device__ __forceinline__ f32x4 mfma16(bf16x8 a, bf16x8 b, f32x4 c){
  return __builtin_amdgcn_mfma_f32_16x16x32_bf16(a,b,c,0,0,0);
}
// read 8 contiguous logical cols of swizzled row lr in a [*][128] bf16 LDS tile
__device__ __forceinline__ bf16x8 ldsfrag(const short* buf, int lr, int kbase, int koff){
  const int el = (kbase + koff) ^ ((lr&7)<<3);
  return *(const bf16x8*)(buf + lr*128 + el);
}
// fp8 e4m3 (OCP on gfx950) helpers
__device__ __forceinline__ uint2 enc8_fp8(bf16x8 v){
  int t0 = __builtin_amdgcn_cvt_pk_fp8_f32(bf2f((unsigned short)v[0]), bf2f((unsigned short)v[1]), 0, false);
  t0     = __builtin_amdgcn_cvt_pk_fp8_f32(bf2f((unsigned short)v[2]), bf2f((unsigned short)v[3]), t0, true);
  int t1 = __builtin_amdgcn_cvt_pk_fp8_f32(bf2f((unsigned short)v[4]), bf2f((unsigned short)v[5]), 0, false);
  t1     = __builtin_amdgcn_cvt_pk_fp8_f32(bf2f((unsigned short)v[6]), bf2f((unsigned short)v[7]), t1, true);
  uint2 o; o.x = (unsigned)t0; o.y = (unsigned)t1; return o;
}
__device__ __forceinline__ void dec4_fp8(unsigned u, float* out){
  f32x2 lo = __builtin_amdgcn_cvt_pk_f32_fp8((int)u, false);
  f32x2 hi = __builtin_amdgcn_cvt_pk_f32_fp8((int)u, true);
  out[0]=lo.x; out[1]=lo.y; out[2]=hi.x; out[3]=hi.y;
}
// non-temporal streaming loads (evict-first)
__device__ __forceinline__ uint2 ntload_u2(const unsigned char* p){
  u32x2 v = __builtin_nontemporal_load((const u32x2*)p);
  uint2 o; o.x = v.x; o.y = v.y; return o;
}
__device__ __forceinline__ unsigned ntload_u1(const unsigned char* p){
  return __builtin_nontemporal_load((const unsigned*)p);
}

// ================= encoder mega-kernel: 48 steps x 2 layers + p fused =================
__global__ __launch_bounds__(512,2) void enc_mega(
  const float* __restrict__ xs3,
  const unsigned short* __restrict__ Wc0, const unsigned short* __restrict__ Wc1,
  const unsigned short* __restrict__ Wp,
  const float* __restrict__ bih, const float* __restrict__ bhh,
  const float* __restrict__ attn_b,
  unsigned char* __restrict__ en_s, unsigned char* __restrict__ p_s,
  float* __restrict__ hseed0, float* __restrict__ hseed1)
{
  __shared__ float h0f[ROWS][132];
  __shared__ float h1f[ROWS][132];
  __shared__ short h0b[ROWS][128];
  __shared__ short h1b[ROWS][128];
  __shared__ short xfrag[TSRC][ROWS][8];
  __shared__ short ptile[ROWS][128];

  const int bid  = blockIdx.x;
  const int row0 = bid*ROWS;
  const int tid  = threadIdx.x;
  const int lane = tid & 63;
  const int w    = tid >> 6;
  const int l15  = lane & 15;
  const int q4   = lane >> 4;
  const int koff = q4*8;
  const int jcol = w*16 + l15;

  for (int e=tid; e<ROWS*132; e+=512){ int r=e/132, c=e%132; h0f[r][c]=0.f; h1f[r][c]=0.f; }
  for (int e=tid; e<ROWS*128; e+=512){ ((short*)h0b)[e]=0; ((short*)h1b)[e]=0; }
  for (int e=tid; e<TSRC*ROWS; e+=512){
    int t = e/ROWS, r = e%ROWS;
    const float* s = xs3 + ((size_t)t*NB + row0 + r)*3;
    short* d = &xfrag[t][r][0];
    d[0]=(short)f2bf(s[0]); d[1]=(short)f2bf(s[1]); d[2]=(short)f2bf(s[2]);
    d[3]=0; d[4]=0; d[5]=0; d[6]=0; d[7]=0;
  }

  bf16x8 wb0[5][3], wb1[8][3], wp[4];
  #pragma unroll
  for (int g=0; g<3; g++){
    #pragma unroll
    for (int ks=0; ks<5; ks++)
      wb0[ks][g] = *(const bf16x8*)(Wc0 + (size_t)(g*128 + jcol)*160 + ks*32 + koff);
    #pragma unroll
    for (int ks=0; ks<8; ks++)
      wb1[ks][g] = *(const bf16x8*)(Wc1 + (size_t)(g*128 + jcol)*256 + ks*32 + koff);
  }
  #pragma unroll
  for (int ks=0; ks<4; ks++)
    wp[ks] = *(const bf16x8*)(Wp + (size_t)jcol*128 + ks*32 + koff);

  const float bR0 = bih[jcol]     + bhh[jcol];
  const float bZ0 = bih[128+jcol] + bhh[128+jcol];
  const float bNi0= bih[256+jcol];
  const float bNh0= bhh[256+jcol];
  const float bR1 = bih[384+jcol]     + bhh[384+jcol];
  const float bZ1 = bih[384+128+jcol] + bhh[384+128+jcol];
  const float bNi1= bih[384+256+jcol];
  const float bNh1= bhh[384+256+jcol];
  const float pb  = attn_b[jcol];
  const bf16x8 zz = {0,0,0,0,0,0,0,0};
  const f32x4 z4 = {0.f,0.f,0.f,0.f};

  __syncthreads();

  for (int t=0; t<TSRC; t++){
    // layer 0: A = [h0 | x3 pad] K=160
    f32x4 aR[2],aZ[2],aNh[2],aNi[2];
    #pragma unroll
    for (int m=0;m<2;m++){ aR[m]=z4; aZ[m]=z4; aNh[m]=z4; aNi[m]=z4; }
    #pragma unroll
    for (int m=0;m<2;m++){
      const int lr = m*16 + l15;
      #pragma unroll
      for (int ks=0;ks<4;ks++){
        bf16x8 a = ldsfrag(&h0b[0][0], lr, ks*32, koff);
        aR[m]=mfma16(a,wb0[ks][0],aR[m]);
        aZ[m]=mfma16(a,wb0[ks][1],aZ[m]);
        aNh[m]=mfma16(a,wb0[ks][2],aNh[m]);
      }
      bf16x8 ax = zz;
      if (q4==0) ax = *(const bf16x8*)(&xfrag[t][lr][0]);
      aR[m]=mfma16(ax,wb0[4][0],aR[m]);
      aZ[m]=mfma16(ax,wb0[4][1],aZ[m]);
      aNi[m]=mfma16(ax,wb0[4][2],aNi[m]);
    }
    __syncthreads();
    #pragma unroll
    for (int m=0;m<2;m++){
      #pragma unroll
      for (int rr=0;rr<4;rr++){
        int r = m*16 + q4*4 + rr;
        float rg = sigm(aR[m][rr]+bR0);
        float zgg= sigm(aZ[m][rr]+bZ0);
        float ng = tanhfast(aNi[m][rr]+bNi0 + rg*(aNh[m][rr]+bNh0));
        float hn = (1.f-zgg)*ng + zgg*h0f[r][jcol];
        h0f[r][jcol] = hn;
        h0b[r][jcol ^ ((r&7)<<3)] = (short)f2bf(hn);
      }
    }
    __syncthreads();
    // layer 1: A = [h1 | h0new] K=256
    #pragma unroll
    for (int m=0;m<2;m++){ aR[m]=z4; aZ[m]=z4; aNh[m]=z4; aNi[m]=z4; }
    #pragma unroll
    for (int m=0;m<2;m++){
      const int lr = m*16 + l15;
      #pragma unroll
      for (int ks=0;ks<4;ks++){
        bf16x8 a = ldsfrag(&h1b[0][0], lr, ks*32, koff);
        aR[m]=mfma16(a,wb1[ks][0],aR[m]);
        aZ[m]=mfma16(a,wb1[ks][1],aZ[m]);
        aNh[m]=mfma16(a,wb1[ks][2],aNh[m]);
      }
      #pragma unroll
      for (int ks=0;ks<4;ks++){
        bf16x8 a = ldsfrag(&h0b[0][0], lr, ks*32, koff);
        aR[m]=mfma16(a,wb1[4+ks][0],aR[m]);
        aZ[m]=mfma16(a,wb1[4+ks][1],aZ[m]);
        aNi[m]=mfma16(a,wb1[4+ks][2],aNi[m]);
      }
    }
    __syncthreads();
    #pragma unroll
    for (int m=0;m<2;m++){
      #pragma unroll
      for (int rr=0;rr<4;rr++){
        int r = m*16 + q4*4 + rr;
        float rg = sigm(aR[m][rr]+bR1);
        float zgg= sigm(aZ[m][rr]+bZ1);
        float ng = tanhfast(aNi[m][rr]+bNi1 + rg*(aNh[m][rr]+bNh1));
        float hn = (1.f-zgg)*ng + zgg*h1f[r][jcol];
        h1f[r][jcol] = hn;
        h1b[r][jcol ^ ((r&7)<<3)] = (short)f2bf(hn);
      }
    }
    __syncthreads();
    // p_t = (h1new @ Wp^T + attn_b) * QSCALE   (prescaled for exp2-form tanh)
    f32x4 pacc[2]; pacc[0]=z4; pacc[1]=z4;
    #pragma unroll
    for (int m=0;m<2;m++){
      const int lr = m*16 + l15;
      #pragma unroll
      for (int ks=0;ks<4;ks++){
        bf16x8 a = ldsfrag(&h1b[0][0], lr, ks*32, koff);
        pacc[m]=mfma16(a,wp[ks],pacc[m]);
      }
    }
    #pragma unroll
    for (int m=0;m<2;m++){
      #pragma unroll
      for (int rr=0;rr<4;rr++){
        int r = m*16 + q4*4 + rr;
        ptile[r][jcol] = (short)f2bf((pacc[m][rr] + pb) * QSCALE);
      }
    }
    __syncthreads();
    // coalesced copy-out: en tile + p tile -> fp8
    {
      const int r = tid >> 4, jc = tid & 15, j0 = jc*8;
      bf16x8 ev = *(const bf16x8*)(&h1b[r][j0 ^ ((r&7)<<3)]);
      bf16x8 pv = *(const bf16x8*)(&ptile[r][j0]);
      const size_t base = ((((size_t)bid*TSRC + t)*ROWS + r)<<7) + j0;
      *(uint2*)(en_s + base) = enc8_fp8(ev);
      *(uint2*)(p_s  + base) = enc8_fp8(pv);
    }
  }
  for (int e=tid; e<ROWS*128; e+=512){
    int r = e>>7, c = e&127;
    hseed0[(size_t)(row0+r)*128 + c] = h0f[r][c];
    hseed1[(size_t)(row0+r)*128 + c] = h1f[r][c];
  }
}

// ===== decoder mega-kernel: R8 structure + deep-pipelined NT streaming =====
__global__ __launch_bounds__(512,4) void dec_mega(
  const float* __restrict__ hseed0, const float* __restrict__ hseed1,
  const unsigned short* __restrict__ Ehw, const float* __restrict__ ehb,
  const float* __restrict__ xs3,
  const unsigned short* __restrict__ Wd0, const unsigned short* __restrict__ Wd1,
  const unsigned short* __restrict__ Wq, const float* __restrict__ v_w,
  const float* __restrict__ bih, const float* __restrict__ bhh,
  const unsigned char* __restrict__ en_s, const unsigned char* __restrict__ p_s,
  const float* __restrict__ fcs, const float* __restrict__ ftail,
  float* __restrict__ pred)
{
  __shared__ short hd0b[DR][128];
  __shared__ short hd1b[DR][128];
  __shared__ float qf[DR][132];
  __shared__ float s_lds[TSRC*DR];
  __shared__ short ctxb[DR][128];
  __shared__ float din[DR][4];
  __shared__ float vls[128];

  const int db   = blockIdx.x;
  const int row0 = db*DR;
  const int tid  = threadIdx.x;
  const int lane = tid & 63;
  const int w    = tid >> 6;
  const int l15  = lane & 15;
  const int q4   = lane >> 4;
  const int koff = q4*8;
  const int jcol = w*16 + l15;
  const f32x4 z4 = {0.f,0.f,0.f,0.f};
  const bf16x8 zz = {0,0,0,0,0,0,0,0};
  const size_t sb0 = (size_t)(db>>1)*TSRC*4096 + (size_t)(db&1)*2048;

  if (tid < 128) vls[tid] = v_w[tid];
  if (tid < DR){
    const float* s = xs3 + ((size_t)(TSRC-1)*NB + row0 + tid)*3;
    din[tid][0]=s[0]; din[tid][1]=s[1]; din[tid][2]=s[2];
  }

  float h0reg[4], h1reg[4];

  // ---- hidden-init: hd = tanh(hseed @ Ehw^T + ehb)
  {
    const float bb = ehb[jcol];
    #pragma unroll
    for (int L=0; L<2; L++){
      const float* hs = L ? hseed1 : hseed0;
      f32x4 acc = z4;
      #pragma unroll
      for (int ks=0;ks<4;ks++){
        const float* ap = hs + (size_t)(row0+l15)*128 + ks*32 + koff;
        float4 f0 = *(const float4*)(ap);
        float4 f1 = *(const float4*)(ap+4);
        bf16x8 a;
        a[0]=(short)f2bf(f0.x); a[1]=(short)f2bf(f0.y); a[2]=(short)f2bf(f0.z); a[3]=(short)f2bf(f0.w);
        a[4]=(short)f2bf(f1.x); a[5]=(short)f2bf(f1.y); a[6]=(short)f2bf(f1.z); a[7]=(short)f2bf(f1.w);
        bf16x8 b = *(const bf16x8*)(Ehw + (size_t)jcol*128 + ks*32 + koff);
        acc = mfma16(a,b,acc);
      }
      #pragma unroll
      for (int rr=0;rr<4;rr++){
        int r = q4*4 + rr;
        float v = tanhfast(acc[rr] + bb);
        if (L) h1reg[rr] = v; else h0reg[rr] = v;
        short hb = (short)f2bf(v);
        if (L) hd1b[r][jcol ^ ((r&7)<<3)] = hb;
        else   hd0b[r][jcol ^ ((r&7)<<3)] = hb;
      }
    }
  }

  const float bR0 = bih[jcol]     + bhh[jcol];
  const float bZ0 = bih[128+jcol] + bhh[128+jcol];
  const float bNi0= bih[256+jcol];
  const float bNh0= bhh[256+jcol];
  const float bR1 = bih[384+jcol]     + bhh[384+jcol];
  const float bZ1 = bih[384+128+jcol] + bhh[384+128+jcol];
  const float bNi1= bih[384+256+jcol];
  const float bNh1= bhh[384+256+jcol];

  __syncthreads();

  // per-lane v slice + its sum (scores: s = Vpart - 2*sum v_j*rcp(exp2+1))
  const int jr = l15*8;
  float vreg[8]; float Vpart = 0.f;
  #pragma unroll
  for (int e=0;e<8;e++){ vreg[e] = vls[jr+e]; Vpart += vreg[e]; }

  for (int t=0; t<TTGT; t++){
    // ---- q' = (hd1b @ Wq^T) * QSCALE -> qf[r][j]  (Wq streamed, L2-cached)
    {
      f32x4 qa = z4;
      #pragma unroll
      for (int ks=0;ks<4;ks++){
        bf16x8 a = ldsfrag(&hd1b[0][0], l15, ks*32, koff);
        bf16x8 b = *(const bf16x8*)(Wq + (size_t)jcol*128 + ks*32 + koff);
        qa = mfma16(a,b,qa);
      }
      #pragma unroll
      for (int rr=0;rr<4;rr++)
        qf[q4*4+rr][jcol] = qa[rr] * QSCALE;
    }
    __syncthreads();
    // ---- scores: wave w owns t-rows 6w..6w+5; 16 rows each; double-buffered
    // groups of 4 NT loads (4-8 outstanding) to hide L3/HBM latency.
    {
      const unsigned char* pp = p_s + sb0;
      auto score1 = [&](uint2 v, int g, int j){
        const int r = j*4 + q4;
        const float4 q0 = *(const float4*)(&qf[r][jr]);
        const float4 q1 = *(const float4*)(&qf[r][jr+4]);
        float pd[8];
        dec4_fp8(v.x, pd); dec4_fp8(v.y, pd+4);
        float s2 = 0.f;
        s2 = fmaf(vreg[0], __builtin_amdgcn_rcpf(__builtin_amdgcn_exp2f(pd[0]+q0.x)+1.f), s2);
        s2 = fmaf(vreg[1], __builtin_amdgcn_rcpf(__builtin_amdgcn_exp2f(pd[1]+q0.y)+1.f), s2);
        s2 = fmaf(vreg[2], __builtin_amdgcn_rcpf(__builtin_amdgcn_exp2f(pd[2]+q0.z)+1.f), s2);
        s2 = fmaf(vreg[3], __builtin_amdgcn_rcpf(__builtin_amdgcn_exp2f(pd[3]+q0.w)+1.f), s2);
        s2 = fmaf(vreg[4], __builtin_amdgcn_rcpf(__builtin_amdgcn_exp2f(pd[4]+q1.x)+1.f), s2);
        s2 = fmaf(vreg[5], __builtin_amdgcn_rcpf(__builtin_amdgcn_exp2f(pd[5]+q1.y)+1.f), s2);
        s2 = fmaf(vreg[6], __builtin_amdgcn_rcpf(__builtin_amdgcn_exp2f(pd[6]+q1.z)+1.f), s2);
        s2 = fmaf(vreg[7], __builtin_amdgcn_rcpf(__builtin_amdgcn_exp2f(pd[7]+q1.w)+1.f), s2);
        float sl = Vpart - 2.f*s2;
        sl += __shfl_xor(sl, 1); sl += __shfl_xor(sl, 2);
        sl += __shfl_xor(sl, 4); sl += __shfl_xor(sl, 8);
        if (l15 == 0) s_lds[(6*w + g)*16 + r] = sl;
      };
      uint2 va[4], vb[4];
      #pragma unroll
      for (int j=0;j<4;j++)
        va[j] = ntload_u2(pp + (size_t)(6*w)*4096 + (j*4+q4)*128 + jr);
      #pragma unroll
      for (int gp=0; gp<3; gp++){
        const int g0 = 2*gp, g1 = 2*gp+1;
        #pragma unroll
        for (int j=0;j<4;j++)
          vb[j] = ntload_u2(pp + (size_t)(6*w+g1)*4096 + (j*4+q4)*128 + jr);
        #pragma unroll
        for (int j=0;j<4;j++) score1(va[j], g0, j);
        if (gp < 2){
          #pragma unroll
          for (int j=0;j<4;j++)
            va[j] = ntload_u2(pp + (size_t)(6*w+g1+1)*4096 + (j*4+q4)*128 + jr);
        }
        #pragma unroll
        for (int j=0;j<4;j++) score1(vb[j], g1, j);
      }
    }
    __syncthreads();
    // ---- softmax over t (16 rows, 1 thread each)
    if (tid < DR){
      float sv[TSRC]; float mx = -1e30f;
      #pragma unroll
      for (int k=0;k<TSRC;k++){ sv[k] = s_lds[k*DR+tid]; mx = fmaxf(mx, sv[k]); }
      float den = 0.f;
      #pragma unroll
      for (int k=0;k<TSRC;k++){ float e2 = __expf(sv[k]-mx); sv[k]=e2; den += e2; }
      float rd = 1.0f/den;
      #pragma unroll
      for (int k=0;k<TSRC;k++) s_lds[k*DR+tid] = sv[k]*rd;
    }
    __syncthreads();
    // ---- context: wave owns rows {2w, 2w+1}; 8 NT loads in flight per group
    {
      const int cr = 2*w + (lane>>5);
      const int cj = (lane&31)*4;
      const unsigned char* ep = en_s + sb0 + cr*128 + cj;
      float ca0=0.f, ca1=0.f, ca2=0.f, ca3=0.f;
      #pragma unroll
      for (int half=0; half<6; half++){
        unsigned u[8];
        #pragma unroll
        for (int x=0;x<8;x++) u[x] = ntload_u1(ep + (size_t)(half*8+x)*4096);
        #pragma unroll
        for (int x=0;x<8;x++){
          float a = s_lds[(half*8+x)*DR + cr];
          float d[4];
          dec4_fp8(u[x], d);
          ca0 += a*d[0]; ca1 += a*d[1]; ca2 += a*d[2]; ca3 += a*d[3];
        }
      }
      bf16x4 cv;
      cv[0]=(short)f2bf(ca0); cv[1]=(short)f2bf(ca1);
      cv[2]=(short)f2bf(ca2); cv[3]=(short)f2bf(ca3);
      *(bf16x4*)(&ctxb[cr][cj ^ ((cr&7)<<3)]) = cv;
    }
    __syncthreads();
    // ---- GRU d0: A = [hd0 | din pad32 | ctx] K=288, weights streamed (L2-cached)
    {
      f32x4 aR=z4, aZ=z4, aNh=z4, aNi=z4;
      #pragma unroll
      for (int ks=0; ks<9; ks++){
        bf16x8 b0 = *(const bf16x8*)(Wd0 + (size_t)(jcol)*288     + ks*32 + koff);
        bf16x8 b1 = *(const bf16x8*)(Wd0 + (size_t)(128+jcol)*288 + ks*32 + koff);
        bf16x8 b2 = *(const bf16x8*)(Wd0 + (size_t)(256+jcol)*288 + ks*32 + koff);
        bf16x8 a;
        if (ks < 4)       a = ldsfrag(&hd0b[0][0], l15, ks*32, koff);
        else if (ks == 4){
          a = zz;
          if (q4==0){ a[0]=(short)f2bf(din[l15][0]); a[1]=(short)f2bf(din[l15][1]); a[2]=(short)f2bf(din[l15][2]); }
        } else            a = ldsfrag(&ctxb[0][0], l15, (ks-5)*32, koff);
        aR = mfma16(a,b0,aR);
        aZ = mfma16(a,b1,aZ);
        if (ks<4) aNh = mfma16(a,b2,aNh);
        else      aNi = mfma16(a,b2,aNi);
      }
      __syncthreads();
      #pragma unroll
      for (int rr=0;rr<4;rr++){
        int r = q4*4 + rr;
        float rg = sigm(aR[rr]+bR0);
        float zg = sigm(aZ[rr]+bZ0);
        float ng = tanhfast(aNi[rr]+bNi0 + rg*(aNh[rr]+bNh0));
        float hn = (1.f-zg)*ng + zg*h0reg[rr];
        h0reg[rr] = hn;
        hd0b[r][jcol ^ ((r&7)<<3)] = (short)f2bf(hn);
      }
    }
    __syncthreads();
    // ---- GRU d1: A = [hd1 | hd0new] K=256, weights streamed (L2-cached)
    {
      f32x4 aR=z4, aZ=z4, aNh=z4, aNi=z4;
      #pragma unroll
      for (int ks=0; ks<8; ks++){
        bf16x8 b0 = *(const bf16x8*)(Wd1 + (size_t)(jcol)*256     + ks*32 + koff);
        bf16x8 b1 = *(const bf16x8*)(Wd1 + (size_t)(128+jcol)*256 + ks*32 + koff);
        bf16x8 b2 = *(const bf16x8*)(Wd1 + (size_t)(256+jcol)*256 + ks*32 + koff);
        bf16x8 a = (ks<4) ? ldsfrag(&hd1b[0][0], l15, ks*32, koff)
                          : ldsfrag(&hd0b[0][0], l15, (ks-4)*32, koff);
        aR = mfma16(a,b0,aR);
        aZ = mfma16(a,b1,aZ);
        if (ks<4) aNh = mfma16(a,b2,aNh);
        else      aNi = mfma16(a,b2,aNi);
      }
      __syncthreads();
      #pragma unroll
      for (int rr=0;rr<4;rr++){
        int r = q4*4 + rr;
        float rg = sigm(aR[rr]+bR1);
        float zg = sigm(aZ[rr]+bZ1);
        float ng = tanhfast(aNi[rr]+bNi1 + rg*(aNh[rr]+bNh1));
        float hn = (1.f-zg)*ng + zg*h1reg[rr];
        h1reg[rr] = hn;
        hd1b[r][jcol ^ ((r&7)<<3)] = (short)f2bf(hn);
      }
    }
    __syncthreads();
    // ---- fc: out = [h1,h1,din]@fc_w^T + fc_b -> pred, din  (folded weights in fcs)
    if (tid < 16*DR){
      const int fr = tid >> 4, fu = tid & 15, fj0 = fu*8;
      bf16x8 hv8 = *(const bf16x8*)(&hd1b[fr][fj0 ^ ((fr&7)<<3)]);
      float hv[8];
      #pragma unroll
      for (int e=0;e<8;e++) hv[e] = bf2f((unsigned short)hv8[e]);
      float o0=0.f,o1=0.f,o2=0.f;
      {
        float4 wa = *(const float4*)(fcs + fj0);
        float4 wb = *(const float4*)(fcs + fj0 + 4);
        o0 = wa.x*hv[0]+wa.y*hv[1]+wa.z*hv[2]+wa.w*hv[3]
           + wb.x*hv[4]+wb.y*hv[5]+wb.z*hv[6]+wb.w*hv[7];
      }
      {
        float4 wa = *(const float4*)(fcs + 132 + fj0);
        float4 wb = *(const float4*)(fcs + 132 + fj0 + 4);
        o1 = wa.x*hv[0]+wa.y*hv[1]+wa.z*hv[2]+wa.w*hv[3]
           + wb.x*hv[4]+wb.y*hv[5]+wb.z*hv[6]+wb.w*hv[7];
      }
      {
        float4 wa = *(const float4*)(fcs + 264 + fj0);
        float4 wb = *(const float4*)(fcs + 264 + fj0 + 4);
        o2 = wa.x*hv[0]+wa.y*hv[1]+wa.z*hv[2]+wa.w*hv[3]
           + wb.x*hv[4]+wb.y*hv[5]+wb.z*hv[6]+wb.w*hv[7];
      }
      #pragma unroll
      for (int off=1; off<16; off<<=1){
        o0 += __shfl_xor(o0, off);
        o1 += __shfl_xor(o1, off);
        o2 += __shfl_xor(o2, off);
      }
      if (fu == 0){
        float d0 = din[fr][0], d1 = din[fr][1], d2 = din[fr][2];
        o0 += ftail[3]  + ftail[0]*d0 + ftail[1]*d1 + ftail[2]*d2;
        o1 += ftail[7]  + ftail[4]*d0 + ftail[5]*d1 + ftail[6]*d2;
        o2 += ftail[11] + ftail[8]*d0 + ftail[9]*d1 + ftail[10]*d2;
        const int nb = row0 + fr;
        const int n = nb >> 6, b = nb & 63;
        float* pr = pred + ((size_t)(b*128 + n)*TTGT + t)*3;
        __builtin_nontemporal_store(o0, pr);
        __builtin_nontemporal_store(o1, pr+1);
        __builtin_nontemporal_store(o2, pr+2);
        din[fr][0]=o0; din[fr][1]=o1; din[fr][2]=o2;
      }
    }
    __syncthreads();
  }
}

// ================= weight preparation =================
__global__ __launch_bounds__(256) void build_kernel(
  const float* __restrict__ e_ih0, const float* __restrict__ e_ih1,
  const float* __restrict__ e_hh,
  const float* __restrict__ d_ih0, const float* __restrict__ d_ih1,
  const float* __restrict__ d_hh,
  const float* __restrict__ attn_w, const float* __restrict__ ehw_f,
  const float* __restrict__ fc_w, const float* __restrict__ fc_b,
  unsigned short* __restrict__ Wc_e0, unsigned short* __restrict__ Wc_e1,
  unsigned short* __restrict__ Wc_d0, unsigned short* __restrict__ Wc_d1,
  unsigned short* __restrict__ Wq, unsigned short* __restrict__ Wp,
  unsigned short* __restrict__ Ehw,
  float* __restrict__ fcs, float* __restrict__ ftail)
{
  int idx = blockIdx.x*256 + threadIdx.x;
  if (idx >= 418200) return;
  if (idx < 61440){
    int j = idx/160, k = idx%160;
    float v = (k<128) ? e_hh[(size_t)j*128 + k]
            : (k<131) ? e_ih0[j*3 + (k-128)] : 0.0f;
    Wc_e0[idx] = f2bf(v);
  } else if (idx < 159744){
    int i = idx - 61440; int j = i/256, k = i%256;
    float v = (k<128) ? e_hh[(size_t)(384 + j)*128 + k]
                      : e_ih1[(size_t)j*128 + (k-128)];
    Wc_e1[i] = f2bf(v);
  } else if (idx < 270336){
    int i = idx - 159744; int j = i/288, k = i%288;
    float v = (k<128) ? d_hh[(size_t)j*128 + k]
            : (k<131) ? d_ih0[(size_t)j*131 + (k-128)]
            : (k<160) ? 0.0f
                      : d_ih0[(size_t)j*131 + 3 + (k-160)];
    Wc_d0[i] = f2bf(v);
  } else if (idx < 368640){
    int i = idx - 270336; int j = i/256, k = i%256;
    float v = (k<128) ? d_hh[(size_t)(384 + j)*128 + k]
                      : d_ih1[(size_t)j*128 + (k-128)];
    Wc_d1[i] = f2bf(v);
  } else if (idx < 385024){
    int i = idx - 368640; int j = i/128, k = i%128;
    Wq[i] = f2bf(attn_w[(size_t)j*256 + k]);
  } else if (idx < 401408){
    int i = idx - 385024; int j = i/128, k = i%128;
    Wp[i] = f2bf(attn_w[(size_t)j*256 + 128 + k]);
  } else if (idx < 417792){
    int i = idx - 401408;
    Ehw[i] = f2bf(ehw_f[i]);
  } else if (idx < 418188){
    int i = idx - 417792; int g = i/132, j = i%132;
    fcs[i] = (j<128) ? (fc_w[(size_t)g*259 + j] + fc_w[(size_t)g*259 + 128 + j]) : 0.0f;
  } else {
    int i = idx - 418188; int g = i/4, e = i%4;
    ftail[i] = (e<3) ? fc_w[(size_t)g*259 + 256 + e] : fc_b[g];
  }
}

__global__ __launch_bounds__(256) void pack_kernel(
  const float* __restrict__ fx, float* __restrict__ xs3)
{
  int idx = blockIdx.x*256 + threadIdx.x;
  if (idx >= TSRC*NB) return;
  int nb = idx & (NB-1), t = idx >> 13;
  int n = nb >> 6, b = nb & 63;
  const float* s = fx + (((size_t)(b*128) + n)*TSRC + t)*3;
  float* d = xs3 + (size_t)idx*3;
  d[0]=s[0]; d[1]=s[1]; d[2]=s[2];
}

extern "C" void kernel_launch(void* const* d_in, const int* in_sizes, int n_in,
                              void* d_out, int out_size, void* d_ws, size_t ws_size,
                              hipStream_t stream)
{
  const float* flow_x   = (const float*)d_in[0];
  const float* flow_y   = (const float*)d_in[1];
  const float* enc_w_ih0= (const float*)d_in[2];
  const float* enc_w_ih1= (const float*)d_in[3];
  const float* enc_w_hh = (const float*)d_in[4];
  const float* enc_b_ih = (const float*)d_in[5];
  const float* enc_b_hh = (const float*)d_in[6];
  const float* enc_hid_w= (const float*)d_in[7];
  const float* enc_hid_b= (const float*)d_in[8];
  const float* dec_w_ih0= (const float*)d_in[9];
  const float* dec_w_ih1= (const float*)d_in[10];
  const float* dec_w_hh = (const float*)d_in[11];
  const float* dec_b_ih = (const float*)d_in[12];
  const float* dec_b_hh = (const float*)d_in[13];
  const float* attn_w   = (const float*)d_in[14];
  const float* attn_b   = (const float*)d_in[15];
  const float* v_w      = (const float*)d_in[16];
  const float* fc_w     = (const float*)d_in[17];
  const float* fc_b     = (const float*)d_in[18];

  float* out_pred = (float*)d_out;
  float* out_fy   = out_pred + (size_t)64*128*TTGT*3;

  char* ws = (char*)d_ws;
  size_t off = 0;
  auto alloc = [&](size_t bytes)->void* {
    void* pp = ws + off; off += (bytes + 255) & ~(size_t)255; return pp;
  };
  float*          xs3    = (float*)alloc((size_t)TSRC*NB*3*4);
  unsigned char*  en_s   = (unsigned char*)alloc((size_t)TSRC*NB*128);
  unsigned char*  p_s    = (unsigned char*)alloc((size_t)TSRC*NB*128);
  float*          hseed0 = (float*)alloc((size_t)NB*128*4);
  float*          hseed1 = (float*)alloc((size_t)NB*128*4);
  unsigned short* Wc_e0  = (unsigned short*)alloc((size_t)384*160*2);
  unsigned short* Wc_e1  = (unsigned short*)alloc((size_t)384*256*2);
  unsigned short* Wc_d0  = (unsigned short*)alloc((size_t)384*288*2);
  unsigned short* Wc_d1  = (unsigned short*)alloc((size_t)384*256*2);
  unsigned short* attnWq = (unsigned short*)alloc((size_t)128*128*2);
  unsigned short* attnWp = (unsigned short*)alloc((size_t)128*128*2);
  unsigned short* Ehw    = (unsigned short*)alloc((size_t)128*128*2);
  float*          fcs    = (float*)alloc((size_t)3*132*4);
  float*          ftail  = (float*)alloc((size_t)12*4);

  hipMemcpyAsync(out_fy, flow_y, (size_t)64*128*TTGT*3*4,
                 hipMemcpyDeviceToDevice, stream);
  build_kernel<<<1634, 256, 0, stream>>>(
      enc_w_ih0, enc_w_ih1, enc_w_hh, dec_w_ih0, dec_w_ih1, dec_w_hh,
      attn_w, enc_hid_w, fc_w, fc_b,
      Wc_e0, Wc_e1, Wc_d0, Wc_d1, attnWq, attnWp, Ehw, fcs, ftail);
  pack_kernel<<<1536, 256, 0, stream>>>(flow_x, xs3);

  enc_mega<<<NB/ROWS, 512, 0, stream>>>(
      xs3, Wc_e0, Wc_e1, attnWp, enc_b_ih, enc_b_hh, attn_b,
      en_s, p_s, hseed0, hseed1);

  dec_mega<<<NB/DR, 512, 0, stream>>>(
      hseed0, hseed1, Ehw, enc_hid_b, xs3, Wc_d0, Wc_d1, attnWq, v_w,
      dec_b_ih, dec_b_hh, en_s, p_s, fcs, ftail, out_pred);
}

// Round 14
// 1104.284 us; speedup vs baseline: 2.0988x; 2.0988x over previous
//
#include <hip/hip_runtime.h>
#include <hip/hip_bf16.h>
#include <math.h>

#define NB   8192
#define TSRC 48
#define TTGT 12
#define ROWS 32      // encoder rows/block
#define DR   16      // decoder rows/block

typedef float f32x4 __attribute__((ext_vector_type(4)));
typedef float f32x2 __attribute__((ext_vector_type(2)));
typedef short bf16x8 __attribute__((ext_vector_type(8)));
typedef short bf16x4 __attribute__((ext_vector_type(4)));
typedef unsigned u32x2 __attribute__((ext_vector_type(2)));

#define QSCALE 2.8853900817779268f   // 2*log2(e)

__device__ __forceinline__ float bf2f(unsigned short u){ return __uint_as_float(((unsigned)u)<<16); }
__device__ __forceinline__ unsigned short f2bf(float f){
  unsigned u = __float_as_uint(f);
  u += 0x7fffu + ((u>>16)&1u);
  return (unsigned short)(u>>16);
}
__device__ __forceinline__ float sigm(float x){ return 1.0f/(1.0f+__expf(-x)); }
__device__ __forceinline__ float tanhfast(float x){
  float a = fminf(fabsf(x), 15.0f);
  float e = __expf(2.0f*a);
  float r = 1.0f - 2.0f/(e+1.0f);
  return copysignf(r, x);
}
__device__ __forceinline__ f32x4 mfma16(bf16x8 a, bf16x8 b, f32x4 c){
  return __builtin_amdgcn_mfma_f32_16x16x32_bf16(a,b,c,0,0,0);
}
// read 8 contiguous logical cols of swizzled row lr in a [*][128] bf16 LDS tile
__device__ __forceinline__ bf16x8 ldsfrag(const short* buf, int lr, int kbase, int koff){
  const int el = (kbase + koff) ^ ((lr&7)<<3);
  return *(const bf16x8*)(buf + lr*128 + el);
}
// fp8 e4m3 (OCP on gfx950) helpers
__device__ __forceinline__ uint2 enc8_fp8(bf16x8 v){
  int t0 = __builtin_amdgcn_cvt_pk_fp8_f32(bf2f((unsigned short)v[0]), bf2f((unsigned short)v[1]), 0, false);
  t0     = __builtin_amdgcn_cvt_pk_fp8_f32(bf2f((unsigned short)v[2]), bf2f((unsigned short)v[3]), t0, true);
  int t1 = __builtin_amdgcn_cvt_pk_fp8_f32(bf2f((unsigned short)v[4]), bf2f((unsigned short)v[5]), 0, false);
  t1     = __builtin_amdgcn_cvt_pk_fp8_f32(bf2f((unsigned short)v[6]), bf2f((unsigned short)v[7]), t1, true);
  uint2 o; o.x = (unsigned)t0; o.y = (unsigned)t1; return o;
}
__device__ __forceinline__ void dec4_fp8(unsigned u, float* out){
  f32x2 lo = __builtin_amdgcn_cvt_pk_f32_fp8((int)u, false);
  f32x2 hi = __builtin_amdgcn_cvt_pk_f32_fp8((int)u, true);
  out[0]=lo.x; out[1]=lo.y; out[2]=hi.x; out[3]=hi.y;
}
// non-temporal streaming loads (evict-first)
__device__ __forceinline__ uint2 ntload_u2(const unsigned char* p){
  u32x2 v = __builtin_nontemporal_load((const u32x2*)p);
  uint2 o; o.x = v.x; o.y = v.y; return o;
}
__device__ __forceinline__ unsigned ntload_u1(const unsigned char* p){
  return __builtin_nontemporal_load((const unsigned*)p);
}

// ================= encoder mega-kernel: 48 steps x 2 layers + p fused =================
__global__ __launch_bounds__(512,2) void enc_mega(
  const float* __restrict__ xs3,
  const unsigned short* __restrict__ Wc0, const unsigned short* __restrict__ Wc1,
  const unsigned short* __restrict__ Wp,
  const float* __restrict__ bih, const float* __restrict__ bhh,
  const float* __restrict__ attn_b,
  unsigned char* __restrict__ en_s, unsigned char* __restrict__ p_s,
  float* __restrict__ hseed0, float* __restrict__ hseed1)
{
  __shared__ float h0f[ROWS][132];
  __shared__ float h1f[ROWS][132];
  __shared__ short h0b[ROWS][128];
  __shared__ short h1b[ROWS][128];
  __shared__ short xfrag[TSRC][ROWS][8];
  __shared__ short ptile[ROWS][128];

  const int bid  = blockIdx.x;
  const int row0 = bid*ROWS;
  const int tid  = threadIdx.x;
  const int lane = tid & 63;
  const int w    = tid >> 6;
  const int l15  = lane & 15;
  const int q4   = lane >> 4;
  const int koff = q4*8;
  const int jcol = w*16 + l15;

  for (int e=tid; e<ROWS*132; e+=512){ int r=e/132, c=e%132; h0f[r][c]=0.f; h1f[r][c]=0.f; }
  for (int e=tid; e<ROWS*128; e+=512){ ((short*)h0b)[e]=0; ((short*)h1b)[e]=0; }
  for (int e=tid; e<TSRC*ROWS; e+=512){
    int t = e/ROWS, r = e%ROWS;
    const float* s = xs3 + ((size_t)t*NB + row0 + r)*3;
    short* d = &xfrag[t][r][0];
    d[0]=(short)f2bf(s[0]); d[1]=(short)f2bf(s[1]); d[2]=(short)f2bf(s[2]);
    d[3]=0; d[4]=0; d[5]=0; d[6]=0; d[7]=0;
  }

  bf16x8 wb0[5][3], wb1[8][3], wp[4];
  #pragma unroll
  for (int g=0; g<3; g++){
    #pragma unroll
    for (int ks=0; ks<5; ks++)
      wb0[ks][g] = *(const bf16x8*)(Wc0 + (size_t)(g*128 + jcol)*160 + ks*32 + koff);
    #pragma unroll
    for (int ks=0; ks<8; ks++)
      wb1[ks][g] = *(const bf16x8*)(Wc1 + (size_t)(g*128 + jcol)*256 + ks*32 + koff);
  }
  #pragma unroll
  for (int ks=0; ks<4; ks++)
    wp[ks] = *(const bf16x8*)(Wp + (size_t)jcol*128 + ks*32 + koff);

  const float bR0 = bih[jcol]     + bhh[jcol];
  const float bZ0 = bih[128+jcol] + bhh[128+jcol];
  const float bNi0= bih[256+jcol];
  const float bNh0= bhh[256+jcol];
  const float bR1 = bih[384+jcol]     + bhh[384+jcol];
  const float bZ1 = bih[384+128+jcol] + bhh[384+128+jcol];
  const float bNi1= bih[384+256+jcol];
  const float bNh1= bhh[384+256+jcol];
  const float pb  = attn_b[jcol];
  const bf16x8 zz = {0,0,0,0,0,0,0,0};
  const f32x4 z4 = {0.f,0.f,0.f,0.f};

  __syncthreads();

  for (int t=0; t<TSRC; t++){
    // layer 0: A = [h0 | x3 pad] K=160
    f32x4 aR[2],aZ[2],aNh[2],aNi[2];
    #pragma unroll
    for (int m=0;m<2;m++){ aR[m]=z4; aZ[m]=z4; aNh[m]=z4; aNi[m]=z4; }
    #pragma unroll
    for (int m=0;m<2;m++){
      const int lr = m*16 + l15;
      #pragma unroll
      for (int ks=0;ks<4;ks++){
        bf16x8 a = ldsfrag(&h0b[0][0], lr, ks*32, koff);
        aR[m]=mfma16(a,wb0[ks][0],aR[m]);
        aZ[m]=mfma16(a,wb0[ks][1],aZ[m]);
        aNh[m]=mfma16(a,wb0[ks][2],aNh[m]);
      }
      bf16x8 ax = zz;
      if (q4==0) ax = *(const bf16x8*)(&xfrag[t][lr][0]);
      aR[m]=mfma16(ax,wb0[4][0],aR[m]);
      aZ[m]=mfma16(ax,wb0[4][1],aZ[m]);
      aNi[m]=mfma16(ax,wb0[4][2],aNi[m]);
    }
    __syncthreads();
    #pragma unroll
    for (int m=0;m<2;m++){
      #pragma unroll
      for (int rr=0;rr<4;rr++){
        int r = m*16 + q4*4 + rr;
        float rg = sigm(aR[m][rr]+bR0);
        float zgg= sigm(aZ[m][rr]+bZ0);
        float ng = tanhfast(aNi[m][rr]+bNi0 + rg*(aNh[m][rr]+bNh0));
        float hn = (1.f-zgg)*ng + zgg*h0f[r][jcol];
        h0f[r][jcol] = hn;
        h0b[r][jcol ^ ((r&7)<<3)] = (short)f2bf(hn);
      }
    }
    __syncthreads();
    // layer 1: A = [h1 | h0new] K=256
    #pragma unroll
    for (int m=0;m<2;m++){ aR[m]=z4; aZ[m]=z4; aNh[m]=z4; aNi[m]=z4; }
    #pragma unroll
    for (int m=0;m<2;m++){
      const int lr = m*16 + l15;
      #pragma unroll
      for (int ks=0;ks<4;ks++){
        bf16x8 a = ldsfrag(&h1b[0][0], lr, ks*32, koff);
        aR[m]=mfma16(a,wb1[ks][0],aR[m]);
        aZ[m]=mfma16(a,wb1[ks][1],aZ[m]);
        aNh[m]=mfma16(a,wb1[ks][2],aNh[m]);
      }
      #pragma unroll
      for (int ks=0;ks<4;ks++){
        bf16x8 a = ldsfrag(&h0b[0][0], lr, ks*32, koff);
        aR[m]=mfma16(a,wb1[4+ks][0],aR[m]);
        aZ[m]=mfma16(a,wb1[4+ks][1],aZ[m]);
        aNi[m]=mfma16(a,wb1[4+ks][2],aNi[m]);
      }
    }
    __syncthreads();
    #pragma unroll
    for (int m=0;m<2;m++){
      #pragma unroll
      for (int rr=0;rr<4;rr++){
        int r = m*16 + q4*4 + rr;
        float rg = sigm(aR[m][rr]+bR1);
        float zgg= sigm(aZ[m][rr]+bZ1);
        float ng = tanhfast(aNi[m][rr]+bNi1 + rg*(aNh[m][rr]+bNh1));
        float hn = (1.f-zgg)*ng + zgg*h1f[r][jcol];
        h1f[r][jcol] = hn;
        h1b[r][jcol ^ ((r&7)<<3)] = (short)f2bf(hn);
      }
    }
    __syncthreads();
    // p_t = (h1new @ Wp^T + attn_b) * QSCALE   (prescaled for exp2-form tanh)
    f32x4 pacc[2]; pacc[0]=z4; pacc[1]=z4;
    #pragma unroll
    for (int m=0;m<2;m++){
      const int lr = m*16 + l15;
      #pragma unroll
      for (int ks=0;ks<4;ks++){
        bf16x8 a = ldsfrag(&h1b[0][0], lr, ks*32, koff);
        pacc[m]=mfma16(a,wp[ks],pacc[m]);
      }
    }
    #pragma unroll
    for (int m=0;m<2;m++){
      #pragma unroll
      for (int rr=0;rr<4;rr++){
        int r = m*16 + q4*4 + rr;
        ptile[r][jcol] = (short)f2bf((pacc[m][rr] + pb) * QSCALE);
      }
    }
    __syncthreads();
    // coalesced copy-out: en tile + p tile -> fp8
    {
      const int r = tid >> 4, jc = tid & 15, j0 = jc*8;
      bf16x8 ev = *(const bf16x8*)(&h1b[r][j0 ^ ((r&7)<<3)]);
      bf16x8 pv = *(const bf16x8*)(&ptile[r][j0]);
      const size_t base = ((((size_t)bid*TSRC + t)*ROWS + r)<<7) + j0;
      *(uint2*)(en_s + base) = enc8_fp8(ev);
      *(uint2*)(p_s  + base) = enc8_fp8(pv);
    }
  }
  for (int e=tid; e<ROWS*128; e+=512){
    int r = e>>7, c = e&127;
    hseed0[(size_t)(row0+r)*128 + c] = h0f[r][c];
    hseed1[(size_t)(row0+r)*128 + c] = h1f[r][c];
  }
}

// ===== decoder (R8 structure): lean regs, streamed weights, NT loads,
// bf16 q/score LDS (20.7 KB -> 3 blocks/CU), wave-parallel softmax =====
__global__ __launch_bounds__(512,4) void dec_mega(
  const float* __restrict__ hseed0, const float* __restrict__ hseed1,
  const unsigned short* __restrict__ Ehw, const float* __restrict__ ehb,
  const float* __restrict__ xs3,
  const unsigned short* __restrict__ Wd0, const unsigned short* __restrict__ Wd1,
  const unsigned short* __restrict__ Wq, const float* __restrict__ v_w,
  const float* __restrict__ bih, const float* __restrict__ bhh,
  const unsigned char* __restrict__ en_s, const unsigned char* __restrict__ p_s,
  const float* __restrict__ fcs, const float* __restrict__ ftail,
  float* __restrict__ pred)
{
  __shared__ short hd0b[DR][128];
  __shared__ short hd1b[DR][128];
  __shared__ unsigned short qfb[DR][128];    // bf16 q' (was f32[16][132])
  __shared__ unsigned short s16[TSRC*DR];    // bf16 scores / softmax weights
  __shared__ short ctxb[DR][128];
  __shared__ float din[DR][4];
  __shared__ float vls[128];

  const int db   = blockIdx.x;
  const int row0 = db*DR;
  const int tid  = threadIdx.x;
  const int lane = tid & 63;
  const int w    = tid >> 6;
  const int l15  = lane & 15;
  const int q4   = lane >> 4;
  const int koff = q4*8;
  const int jcol = w*16 + l15;
  const f32x4 z4 = {0.f,0.f,0.f,0.f};
  const bf16x8 zz = {0,0,0,0,0,0,0,0};
  const size_t sb0 = (size_t)(db>>1)*TSRC*4096 + (size_t)(db&1)*2048;

  if (tid < 128) vls[tid] = v_w[tid];
  if (tid < DR){
    const float* s = xs3 + ((size_t)(TSRC-1)*NB + row0 + tid)*3;
    din[tid][0]=s[0]; din[tid][1]=s[1]; din[tid][2]=s[2];
  }

  float h0reg[4], h1reg[4];

  // ---- hidden-init: hd = tanh(hseed @ Ehw^T + ehb)
  {
    const float bb = ehb[jcol];
    #pragma unroll
    for (int L=0; L<2; L++){
      const float* hs = L ? hseed1 : hseed0;
      f32x4 acc = z4;
      #pragma unroll
      for (int ks=0;ks<4;ks++){
        const float* ap = hs + (size_t)(row0+l15)*128 + ks*32 + koff;
        float4 f0 = *(const float4*)(ap);
        float4 f1 = *(const float4*)(ap+4);
        bf16x8 a;
        a[0]=(short)f2bf(f0.x); a[1]=(short)f2bf(f0.y); a[2]=(short)f2bf(f0.z); a[3]=(short)f2bf(f0.w);
        a[4]=(short)f2bf(f1.x); a[5]=(short)f2bf(f1.y); a[6]=(short)f2bf(f1.z); a[7]=(short)f2bf(f1.w);
        bf16x8 b = *(const bf16x8*)(Ehw + (size_t)jcol*128 + ks*32 + koff);
        acc = mfma16(a,b,acc);
      }
      #pragma unroll
      for (int rr=0;rr<4;rr++){
        int r = q4*4 + rr;
        float v = tanhfast(acc[rr] + bb);
        if (L) h1reg[rr] = v; else h0reg[rr] = v;
        short hb = (short)f2bf(v);
        if (L) hd1b[r][jcol ^ ((r&7)<<3)] = hb;
        else   hd0b[r][jcol ^ ((r&7)<<3)] = hb;
      }
    }
  }

  const float bR0 = bih[jcol]     + bhh[jcol];
  const float bZ0 = bih[128+jcol] + bhh[128+jcol];
  const float bNi0= bih[256+jcol];
  const float bNh0= bhh[256+jcol];
  const float bR1 = bih[384+jcol]     + bhh[384+jcol];
  const float bZ1 = bih[384+128+jcol] + bhh[384+128+jcol];
  const float bNi1= bih[384+256+jcol];
  const float bNh1= bhh[384+256+jcol];

  __syncthreads();

  // per-lane v slice + its sum (scores: s = Vpart - 2*sum v_j*rcp(exp2+1))
  const int jr = l15*8;
  float vreg[8]; float Vpart = 0.f;
  #pragma unroll
  for (int e=0;e<8;e++){ vreg[e] = vls[jr+e]; Vpart += vreg[e]; }

  for (int t=0; t<TTGT; t++){
    // ---- q' = (hd1b @ Wq^T) * QSCALE -> qfb[r][j] (bf16)
    {
      f32x4 qa = z4;
      #pragma unroll
      for (int ks=0;ks<4;ks++){
        bf16x8 a = ldsfrag(&hd1b[0][0], l15, ks*32, koff);
        bf16x8 b = *(const bf16x8*)(Wq + (size_t)jcol*128 + ks*32 + koff);
        qa = mfma16(a,b,qa);
      }
      #pragma unroll
      for (int rr=0;rr<4;rr++)
        qfb[q4*4+rr][jcol] = f2bf(qa[rr] * QSCALE);
    }
    __syncthreads();
    // ---- scores: wave handles 96 sidx (=t48*16+r) in 24 passes of 4 rows (NT loads)
    {
      int sidx = w*96 + q4;
      const unsigned char* pp = p_s + sb0;
      uint2 pv = ntload_u2(pp + (size_t)(sidx>>4)*4096 + (sidx&15)*128 + jr);
      #pragma unroll 4
      for (int k=0;k<24;k++){
        int snext = sidx + 4;
        uint2 pn = pv;
        if (k < 23)
          pn = ntload_u2(pp + (size_t)(snext>>4)*4096 + (snext&15)*128 + jr);
        const int r = sidx & 15;
        bf16x8 qv = *(const bf16x8*)(&qfb[r][jr]);
        float pd[8];
        dec4_fp8(pv.x, pd); dec4_fp8(pv.y, pd+4);
        float s2 = 0.f;
        s2 = fmaf(vreg[0], __builtin_amdgcn_rcpf(__builtin_amdgcn_exp2f(pd[0]+bf2f((unsigned short)qv[0]))+1.f), s2);
        s2 = fmaf(vreg[1], __builtin_amdgcn_rcpf(__builtin_amdgcn_exp2f(pd[1]+bf2f((unsigned short)qv[1]))+1.f), s2);
        s2 = fmaf(vreg[2], __builtin_amdgcn_rcpf(__builtin_amdgcn_exp2f(pd[2]+bf2f((unsigned short)qv[2]))+1.f), s2);
        s2 = fmaf(vreg[3], __builtin_amdgcn_rcpf(__builtin_amdgcn_exp2f(pd[3]+bf2f((unsigned short)qv[3]))+1.f), s2);
        s2 = fmaf(vreg[4], __builtin_amdgcn_rcpf(__builtin_amdgcn_exp2f(pd[4]+bf2f((unsigned short)qv[4]))+1.f), s2);
        s2 = fmaf(vreg[5], __builtin_amdgcn_rcpf(__builtin_amdgcn_exp2f(pd[5]+bf2f((unsigned short)qv[5]))+1.f), s2);
        s2 = fmaf(vreg[6], __builtin_amdgcn_rcpf(__builtin_amdgcn_exp2f(pd[6]+bf2f((unsigned short)qv[6]))+1.f), s2);
        s2 = fmaf(vreg[7], __builtin_amdgcn_rcpf(__builtin_amdgcn_exp2f(pd[7]+bf2f((unsigned short)qv[7]))+1.f), s2);
        float sl = Vpart - 2.f*s2;
        sl += __shfl_xor(sl, 1); sl += __shfl_xor(sl, 2);
        sl += __shfl_xor(sl, 4); sl += __shfl_xor(sl, 8);
        if (l15 == 0) s16[sidx] = f2bf(sl);
        sidx = snext; pv = pn;
      }
    }
    __syncthreads();
    // ---- softmax over t: wave-parallel; wave w handles rows w and w+8
    {
      #pragma unroll
      for (int h=0; h<2; h++){
        const int r = w + h*8;
        float s = (lane < TSRC) ? bf2f(s16[lane*DR + r]) : -1e30f;
        float mx = s;
        #pragma unroll
        for (int off=32; off>=1; off>>=1) mx = fmaxf(mx, __shfl_xor(mx, off));
        float e2 = (lane < TSRC) ? __expf(s - mx) : 0.f;
        float den = e2;
        #pragma unroll
        for (int off=32; off>=1; off>>=1) den += __shfl_xor(den, off);
        if (lane < TSRC) s16[lane*DR + r] = f2bf(e2 / den);
      }
    }
    __syncthreads();
    // ---- context: wave owns rows {2w, 2w+1}; lane covers 4 j (fp8 en, NT loads)
    {
      const int cr = 2*w + (lane>>5);
      const int cj = (lane&31)*4;
      const unsigned char* ep = en_s + sb0 + cr*128 + cj;
      float ca0=0.f, ca1=0.f, ca2=0.f, ca3=0.f;
      #pragma unroll 3
      for (int tt=0; tt<TSRC; tt+=4){
        unsigned u0 = ntload_u1(ep + (size_t)(tt  )*4096);
        unsigned u1 = ntload_u1(ep + (size_t)(tt+1)*4096);
        unsigned u2 = ntload_u1(ep + (size_t)(tt+2)*4096);
        unsigned u3 = ntload_u1(ep + (size_t)(tt+3)*4096);
        float a0 = bf2f(s16[(tt  )*DR + cr]);
        float a1 = bf2f(s16[(tt+1)*DR + cr]);
        float a2 = bf2f(s16[(tt+2)*DR + cr]);
        float a3 = bf2f(s16[(tt+3)*DR + cr]);
        float d0[4], d1[4], d2[4], d3[4];
        dec4_fp8(u0,d0); dec4_fp8(u1,d1); dec4_fp8(u2,d2); dec4_fp8(u3,d3);
        ca0 += a0*d0[0] + a1*d1[0] + a2*d2[0] + a3*d3[0];
        ca1 += a0*d0[1] + a1*d1[1] + a2*d2[1] + a3*d3[1];
        ca2 += a0*d0[2] + a1*d1[2] + a2*d2[2] + a3*d3[2];
        ca3 += a0*d0[3] + a1*d1[3] + a2*d2[3] + a3*d3[3];
      }
      bf16x4 cv;
      cv[0]=(short)f2bf(ca0); cv[1]=(short)f2bf(ca1);
      cv[2]=(short)f2bf(ca2); cv[3]=(short)f2bf(ca3);
      *(bf16x4*)(&ctxb[cr][cj ^ ((cr&7)<<3)]) = cv;
    }
    __syncthreads();
    // ---- GRU d0: A = [hd0 | din pad32 | ctx] K=288, weights streamed (L2-cached)
    {
      f32x4 aR=z4, aZ=z4, aNh=z4, aNi=z4;
      #pragma unroll
      for (int ks=0; ks<9; ks++){
        bf16x8 b0 = *(const bf16x8*)(Wd0 + (size_t)(jcol)*288     + ks*32 + koff);
        bf16x8 b1 = *(const bf16x8*)(Wd0 + (size_t)(128+jcol)*288 + ks*32 + koff);
        bf16x8 b2 = *(const bf16x8*)(Wd0 + (size_t)(256+jcol)*288 + ks*32 + koff);
        bf16x8 a;
        if (ks < 4)       a = ldsfrag(&hd0b[0][0], l15, ks*32, koff);
        else if (ks == 4){
          a = zz;
          if (q4==0){ a[0]=(short)f2bf(din[l15][0]); a[1]=(short)f2bf(din[l15][1]); a[2]=(short)f2bf(din[l15][2]); }
        } else            a = ldsfrag(&ctxb[0][0], l15, (ks-5)*32, koff);
        aR = mfma16(a,b0,aR);
        aZ = mfma16(a,b1,aZ);
        if (ks<4) aNh = mfma16(a,b2,aNh);
        else      aNi = mfma16(a,b2,aNi);
      }
      __syncthreads();
      #pragma unroll
      for (int rr=0;rr<4;rr++){
        int r = q4*4 + rr;
        float rg = sigm(aR[rr]+bR0);
        float zg = sigm(aZ[rr]+bZ0);
        float ng = tanhfast(aNi[rr]+bNi0 + rg*(aNh[rr]+bNh0));
        float hn = (1.f-zg)*ng + zg*h0reg[rr];
        h0reg[rr] = hn;
        hd0b[r][jcol ^ ((r&7)<<3)] = (short)f2bf(hn);
      }
    }
    __syncthreads();
    // ---- GRU d1: A = [hd1 | hd0new] K=256, weights streamed (L2-cached)
    {
      f32x4 aR=z4, aZ=z4, aNh=z4, aNi=z4;
      #pragma unroll
      for (int ks=0; ks<8; ks++){
        bf16x8 b0 = *(const bf16x8*)(Wd1 + (size_t)(jcol)*256     + ks*32 + koff);
        bf16x8 b1 = *(const bf16x8*)(Wd1 + (size_t)(128+jcol)*256 + ks*32 + koff);
        bf16x8 b2 = *(const bf16x8*)(Wd1 + (size_t)(256+jcol)*256 + ks*32 + koff);
        bf16x8 a = (ks<4) ? ldsfrag(&hd1b[0][0], l15, ks*32, koff)
                          : ldsfrag(&hd0b[0][0], l15, (ks-4)*32, koff);
        aR = mfma16(a,b0,aR);
        aZ = mfma16(a,b1,aZ);
        if (ks<4) aNh = mfma16(a,b2,aNh);
        else      aNi = mfma16(a,b2,aNi);
      }
      __syncthreads();
      #pragma unroll
      for (int rr=0;rr<4;rr++){
        int r = q4*4 + rr;
        float rg = sigm(aR[rr]+bR1);
        float zg = sigm(aZ[rr]+bZ1);
        float ng = tanhfast(aNi[rr]+bNi1 + rg*(aNh[rr]+bNh1));
        float hn = (1.f-zg)*ng + zg*h1reg[rr];
        h1reg[rr] = hn;
        hd1b[r][jcol ^ ((r&7)<<3)] = (short)f2bf(hn);
      }
    }
    __syncthreads();
    // ---- fc: out = [h1,h1,din]@fc_w^T + fc_b -> pred, din  (folded weights in fcs)
    if (tid < 16*DR){
      const int fr = tid >> 4, fu = tid & 15, fj0 = fu*8;
      bf16x8 hv8 = *(const bf16x8*)(&hd1b[fr][fj0 ^ ((fr&7)<<3)]);
      float hv[8];
      #pragma unroll
      for (int e=0;e<8;e++) hv[e] = bf2f((unsigned short)hv8[e]);
      float o0=0.f,o1=0.f,o2=0.f;
      {
        float4 wa = *(const float4*)(fcs + fj0);
        float4 wb = *(const float4*)(fcs + fj0 + 4);
        o0 = wa.x*hv[0]+wa.y*hv[1]+wa.z*hv[2]+wa.w*hv[3]
           + wb.x*hv[4]+wb.y*hv[5]+wb.z*hv[6]+wb.w*hv[7];
      }
      {
        float4 wa = *(const float4*)(fcs + 132 + fj0);
        float4 wb = *(const float4*)(fcs + 132 + fj0 + 4);
        o1 = wa.x*hv[0]+wa.y*hv[1]+wa.z*hv[2]+wa.w*hv[3]
           + wb.x*hv[4]+wb.y*hv[5]+wb.z*hv[6]+wb.w*hv[7];
      }
      {
        float4 wa = *(const float4*)(fcs + 264 + fj0);
        float4 wb = *(const float4*)(fcs + 264 + fj0 + 4);
        o2 = wa.x*hv[0]+wa.y*hv[1]+wa.z*hv[2]+wa.w*hv[3]
           + wb.x*hv[4]+wb.y*hv[5]+wb.z*hv[6]+wb.w*hv[7];
      }
      #pragma unroll
      for (int off=1; off<16; off<<=1){
        o0 += __shfl_xor(o0, off);
        o1 += __shfl_xor(o1, off);
        o2 += __shfl_xor(o2, off);
      }
      if (fu == 0){
        float d0 = din[fr][0], d1 = din[fr][1], d2 = din[fr][2];
        o0 += ftail[3]  + ftail[0]*d0 + ftail[1]*d1 + ftail[2]*d2;
        o1 += ftail[7]  + ftail[4]*d0 + ftail[5]*d1 + ftail[6]*d2;
        o2 += ftail[11] + ftail[8]*d0 + ftail[9]*d1 + ftail[10]*d2;
        const int nb = row0 + fr;
        const int n = nb >> 6, b = nb & 63;
        float* pr = pred + ((size_t)(b*128 + n)*TTGT + t)*3;
        __builtin_nontemporal_store(o0, pr);
        __builtin_nontemporal_store(o1, pr+1);
        __builtin_nontemporal_store(o2, pr+2);
        din[fr][0]=o0; din[fr][1]=o1; din[fr][2]=o2;
      }
    }
    __syncthreads();
  }
}

// ================= weight preparation =================
__global__ __launch_bounds__(256) void build_kernel(
  const float* __restrict__ e_ih0, const float* __restrict__ e_ih1,
  const float* __restrict__ e_hh,
  const float* __restrict__ d_ih0, const float* __restrict__ d_ih1,
  const float* __restrict__ d_hh,
  const float* __restrict__ attn_w, const float* __restrict__ ehw_f,
  const float* __restrict__ fc_w, const float* __restrict__ fc_b,
  unsigned short* __restrict__ Wc_e0, unsigned short* __restrict__ Wc_e1,
  unsigned short* __restrict__ Wc_d0, unsigned short* __restrict__ Wc_d1,
  unsigned short* __restrict__ Wq, unsigned short* __restrict__ Wp,
  unsigned short* __restrict__ Ehw,
  float* __restrict__ fcs, float* __restrict__ ftail)
{
  int idx = blockIdx.x*256 + threadIdx.x;
  if (idx >= 418200) return;
  if (idx < 61440){
    int j = idx/160, k = idx%160;
    float v = (k<128) ? e_hh[(size_t)j*128 + k]
            : (k<131) ? e_ih0[j*3 + (k-128)] : 0.0f;
    Wc_e0[idx] = f2bf(v);
  } else if (idx < 159744){
    int i = idx - 61440; int j = i/256, k = i%256;
    float v = (k<128) ? e_hh[(size_t)(384 + j)*128 + k]
                      : e_ih1[(size_t)j*128 + (k-128)];
    Wc_e1[i] = f2bf(v);
  } else if (idx < 270336){
    int i = idx - 159744; int j = i/288, k = i%288;
    float v = (k<128) ? d_hh[(size_t)j*128 + k]
            : (k<131) ? d_ih0[(size_t)j*131 + (k-128)]
            : (k<160) ? 0.0f
                      : d_ih0[(size_t)j*131 + 3 + (k-160)];
    Wc_d0[i] = f2bf(v);
  } else if (idx < 368640){
    int i = idx - 270336; int j = i/256, k = i%256;
    float v = (k<128) ? d_hh[(size_t)(384 + j)*128 + k]
                      : d_ih1[(size_t)j*128 + (k-128)];
    Wc_d1[i] = f2bf(v);
  } else if (idx < 385024){
    int i = idx - 368640; int j = i/128, k = i%128;
    Wq[i] = f2bf(attn_w[(size_t)j*256 + k]);
  } else if (idx < 401408){
    int i = idx - 385024; int j = i/128, k = i%128;
    Wp[i] = f2bf(attn_w[(size_t)j*256 + 128 + k]);
  } else if (idx < 417792){
    int i = idx - 401408;
    Ehw[i] = f2bf(ehw_f[i]);
  } else if (idx < 418188){
    int i = idx - 417792; int g = i/132, j = i%132;
    fcs[i] = (j<128) ? (fc_w[(size_t)g*259 + j] + fc_w[(size_t)g*259 + 128 + j]) : 0.0f;
  } else {
    int i = idx - 418188; int g = i/4, e = i%4;
    ftail[i] = (e<3) ? fc_w[(size_t)g*259 + 256 + e] : fc_b[g];
  }
}

__global__ __launch_bounds__(256) void pack_kernel(
  const float* __restrict__ fx, float* __restrict__ xs3)
{
  int idx = blockIdx.x*256 + threadIdx.x;
  if (idx >= TSRC*NB) return;
  int nb = idx & (NB-1), t = idx >> 13;
  int n = nb >> 6, b = nb & 63;
  const float* s = fx + (((size_t)(b*128) + n)*TSRC + t)*3;
  float* d = xs3 + (size_t)idx*3;
  d[0]=s[0]; d[1]=s[1]; d[2]=s[2];
}

extern "C" void kernel_launch(void* const* d_in, const int* in_sizes, int n_in,
                              void* d_out, int out_size, void* d_ws, size_t ws_size,
                              hipStream_t stream)
{
  const float* flow_x   = (const float*)d_in[0];
  const float* flow_y   = (const float*)d_in[1];
  const float* enc_w_ih0= (const float*)d_in[2];
  const float* enc_w_ih1= (const float*)d_in[3];
  const float* enc_w_hh = (const float*)d_in[4];
  const float* enc_b_ih = (const float*)d_in[5];
  const float* enc_b_hh = (const float*)d_in[6];
  const float* enc_hid_w= (const float*)d_in[7];
  const float* enc_hid_b= (const float*)d_in[8];
  const float* dec_w_ih0= (const float*)d_in[9];
  const float* dec_w_ih1= (const float*)d_in[10];
  const float* dec_w_hh = (const float*)d_in[11];
  const float* dec_b_ih = (const float*)d_in[12];
  const float* dec_b_hh = (const float*)d_in[13];
  const float* attn_w   = (const float*)d_in[14];
  const float* attn_b   = (const float*)d_in[15];
  const float* v_w      = (const float*)d_in[16];
  const float* fc_w     = (const float*)d_in[17];
  const float* fc_b     = (const float*)d_in[18];

  float* out_pred = (float*)d_out;
  float* out_fy   = out_pred + (size_t)64*128*TTGT*3;

  char* ws = (char*)d_ws;
  size_t off = 0;
  auto alloc = [&](size_t bytes)->void* {
    void* pp = ws + off; off += (bytes + 255) & ~(size_t)255; return pp;
  };
  float*          xs3    = (float*)alloc((size_t)TSRC*NB*3*4);
  unsigned char*  en_s   = (unsigned char*)alloc((size_t)TSRC*NB*128);
  unsigned char*  p_s    = (unsigned char*)alloc((size_t)TSRC*NB*128);
  float*          hseed0 = (float*)alloc((size_t)NB*128*4);
  float*          hseed1 = (float*)alloc((size_t)NB*128*4);
  unsigned short* Wc_e0  = (unsigned short*)alloc((size_t)384*160*2);
  unsigned short* Wc_e1  = (unsigned short*)alloc((size_t)384*256*2);
  unsigned short* Wc_d0  = (unsigned short*)alloc((size_t)384*288*2);
  unsigned short* Wc_d1  = (unsigned short*)alloc((size_t)384*256*2);
  unsigned short* attnWq = (unsigned short*)alloc((size_t)128*128*2);
  unsigned short* attnWp = (unsigned short*)alloc((size_t)128*128*2);
  unsigned short* Ehw    = (unsigned short*)alloc((size_t)128*128*2);
  float*          fcs    = (float*)alloc((size_t)3*132*4);
  float*          ftail  = (float*)alloc((size_t)12*4);

  hipMemcpyAsync(out_fy, flow_y, (size_t)64*128*TTGT*3*4,
                 hipMemcpyDeviceToDevice, stream);
  build_kernel<<<1634, 256, 0, stream>>>(
      enc_w_ih0, enc_w_ih1, enc_w_hh, dec_w_ih0, dec_w_ih1, dec_w_hh,
      attn_w, enc_hid_w, fc_w, fc_b,
      Wc_e0, Wc_e1, Wc_d0, Wc_d1, attnWq, attnWp, Ehw, fcs, ftail);
  pack_kernel<<<1536, 256, 0, stream>>>(flow_x, xs3);

  enc_mega<<<NB/ROWS, 512, 0, stream>>>(
      xs3, Wc_e0, Wc_e1, attnWp, enc_b_ih, enc_b_hh, attn_b,
      en_s, p_s, hseed0, hseed1);

  dec_mega<<<NB/DR, 512, 0, stream>>>(
      hseed0, hseed1, Ehw, enc_hid_b, xs3, Wc_d0, Wc_d1, attnWq, v_w,
      dec_b_ih, dec_b_hh, en_s, p_s, fcs, ftail, out_pred);
}